// Round 4
// baseline (179.130 us; speedup 1.0000x reference)
//
#include <hip/hip_runtime.h>
#include <stdint.h>
#include <math.h>

// ---------------------------------------------------------------------------
// IID segmentation loss on MI355X.  Round 4.
//
// C[(n,dx)][(o,dy)] = sum_{b,y,x} xo[b,n,y,x+dx-7] * xt[b,o,y+7-dy,x]
// R3 (DPP B-in-registers) FAILED: inject-load latency serialized the y chain
// and parity-LDS had 4-way bank conflicts.  R4 returns to R2's proven
// y-outer/xc-inner LDS-B structure and removes its real costs:
//   - A-frags: pre-packed bf16 "apad" in HBM (x-pad baked in, dword-packed).
//     One dwordx4 + one dword (4B-aligned) + 4 alignbit per frag; NO ldsA,
//     NO staging VALU, NO A barriers.  Double-buffered one step ahead.
//   - B: circular 16-slot LDS window, async global_load_lds DMA, ONE barrier
//     per y (slot y+8 last truly read at step y-1; lane-15 read is the
//     discarded phantom dy=15 column).
//   - Tail fused: prep (A+B), reduce (stage1+final+min), loss.  4 launches.
// ---------------------------------------------------------------------------

#define PADV 7
#define TS 15
#define KCLS 10
#define HH 224
#define WW 224
#define MD 160
#define NCELL (MD*MD)
#define NBLK 512
#define TY 7
#define BSTRIDE 232
#define BPH 240
#define ADW 120            // apad dwords per (cls,y) row (240 bf16 elems)
#define LEPS 1e-16

typedef __attribute__((ext_vector_type(4))) float f32x4;
typedef __attribute__((ext_vector_type(8))) short bf16x8;

__device__ __forceinline__ unsigned short f2bf(float f) {
  union { float f; uint32_t u; } v; v.f = f;
  return (unsigned short)((v.u + 0x7FFFu + ((v.u >> 16) & 1u)) >> 16);
}

__device__ __forceinline__ void glds16(const unsigned short* g, unsigned short* l) {
  __builtin_amdgcn_global_load_lds(
      (const __attribute__((address_space(1))) unsigned int*)g,
      (__attribute__((address_space(3))) unsigned int*)l, 16, 0, 0);
}

struct U5 { uint32_t u[5]; };

// 16B load at 4B alignment (global dwordx4 allows dword alignment) + tail dword
__device__ __forceinline__ void ldA5(const uint32_t* p, U5& d) {
  uint4 t;
  __builtin_memcpy(&t, p, 16);
  d.u[0] = t.x; d.u[1] = t.y; d.u[2] = t.z; d.u[3] = t.w;
  d.u[4] = p[4];
}

// ---------------------------------------------------- prep: apad + bpad
// bpad[cls][yy][x] bf16: yy in [0,240) <-> img row yy-7, x in [0,232) (x>=224 pad0)
// apad[cls][y][w] dwords: dword w = (elem[2w], elem[2w+1]), elem[i]=xo[cls,y,i-7]
#define BPREP_BLOCKS 4350   // 160*240*29 threads
#define APREP_BLOCKS 4200   // 160*224*30 threads
__global__ __launch_bounds__(256)
void prep(const float* __restrict__ xo, const float* __restrict__ xt,
          unsigned short* __restrict__ bp, uint32_t* __restrict__ ap) {
  if (blockIdx.x < BPREP_BLOCKS) {
    const int idx   = blockIdx.x * 256 + threadIdx.x;
    const int rowid = idx / 29;
    const int chunk = idx - rowid * 29;
    const int x0    = chunk * 8;
    const int yy    = rowid % BPH;
    const int cls   = rowid / BPH;
    const int row   = yy - PADV;
    union { unsigned short h[8]; uint4 v; } out;
    if (row >= 0 && row < HH && x0 < WW) {
      const float* src = xt + ((size_t)cls * HH + row) * WW + x0;
#pragma unroll
      for (int j = 0; j < 8; ++j) out.h[j] = f2bf(src[j]);
    } else {
      out.v = make_uint4(0u, 0u, 0u, 0u);
    }
    *(uint4*)(bp + (size_t)rowid * BSTRIDE + x0) = out.v;
  } else {
    const int idx   = (blockIdx.x - BPREP_BLOCKS) * 256 + threadIdx.x;
    const int rowid = idx / 30;               // cls*224 + y
    const int wg    = idx - rowid * 30;       // dword group: 4wg..4wg+3
    const float* src = xo + (size_t)rowid * WW;
    float e[8];
#pragma unroll
    for (int j = 0; j < 8; ++j) {
      const int x = 8 * wg + j - PADV;
      e[j] = (x >= 0 && x < WW) ? src[x] : 0.f;
    }
    union { uint32_t u[4]; uint4 v; } o;
#pragma unroll
    for (int k = 0; k < 4; ++k)
      o.u[k] = (uint32_t)f2bf(e[2 * k]) | ((uint32_t)f2bf(e[2 * k + 1]) << 16);
    *(uint4*)(ap + (size_t)rowid * ADW + 4 * wg) = o.v;
  }
}

// ---------------------------------------------------------------- K1: GEMM
__global__ __launch_bounds__(256, 2)
void corr_gemm(const uint32_t* __restrict__ apad,
               const unsigned short* __restrict__ bpad,
               float* __restrict__ partials) {
  __shared__ __align__(16) unsigned short ldsB[KCLS * 16 * BSTRIDE];  // 74240 B

  const int tid  = threadIdx.x;
  const int bid  = blockIdx.x;
  const int b    = bid >> 5;
  const int y0   = (bid & 31) * TY;

  const int lane = tid & 63;
  const int wv   = tid >> 6;
  const int wm   = wv & 1;
  const int wn   = wv >> 1;
  const int quad = lane >> 4;
  const int l15  = lane & 15;

  const int shA    = (l15 & 1) << 4;           // alignbit shift
  const int laneWd = quad * 4 + (l15 >> 1);    // dword offset within row chunk

  f32x4 acc[5][5];
#pragma unroll
  for (int i = 0; i < 5; ++i)
#pragma unroll
    for (int j = 0; j < 5; ++j) acc[i][j] = (f32x4){0.f, 0.f, 0.f, 0.f};

  const unsigned short* Bb = bpad + (size_t)b * KCLS * BPH * BSTRIDE;
  const uint32_t* Abase = apad + ((size_t)(b * KCLS + wm * 5) * HH) * ADW;

  // prologue: async DMA B rows y0-7..y0+7 (150 class-rows)
  for (int pr = wv; pr < 15 * KCLS; pr += 4) {
    const int r15  = pr / KCLS;
    const int o    = pr - r15 * KCLS;
    const int yy   = y0 + r15;
    const int slot = (y0 - PADV + r15) & 15;
    if (lane < 29)
      glds16(Bb + ((size_t)o * BPH + yy) * BSTRIDE + lane * 8,
             ldsB + (o * 16 + slot) * BSTRIDE);
  }

  U5 bufA[5], bufB[5];
  // prefetch t=0 (y=y0, xc=0)
#pragma unroll
  for (int mi = 0; mi < 5; ++mi)
    ldA5(Abase + ((size_t)mi * HH + y0) * ADW + laneWd, bufA[mi]);

  __syncthreads();  // drains prologue DMA (+ prefetch, harmless)

  auto step = [&](int t, U5 (&use)[5], U5 (&pre)[5]) {
    const int ydiv = t / 7;
    const int xc   = t - 7 * ydiv;
    const int y    = y0 + ydiv;

    // B DMA for row y+8 (slot (y+8)&15), once per y, right after the barrier
    if (xc == 0) {
      const int yy   = y + 8 + PADV;
      const int slot = (y + 8) & 15;
      for (int ro = wv; ro < KCLS; ro += 4) {
        if (lane < 29)
          glds16(Bb + ((size_t)ro * BPH + yy) * BSTRIDE + lane * 8,
                 ldsB + (ro * 16 + slot) * BSTRIDE);
      }
    }

    // prefetch A for step t+1
    if (t < 48) {
      const int t1    = t + 1;
      const int ydiv1 = t1 / 7;
      const int xc1   = t1 - 7 * ydiv1;
      const int y1    = y0 + ydiv1;
#pragma unroll
      for (int mi = 0; mi < 5; ++mi)
        ldA5(Abase + ((size_t)mi * HH + y1) * ADW + xc1 * 16 + laneWd, pre[mi]);
    }

    // A-frags from raw dwords (alignbit by lane parity)
    bf16x8 afrag[5];
#pragma unroll
    for (int mi = 0; mi < 5; ++mi) {
      union { uint32_t u[4]; bf16x8 v; } cv;
      cv.u[0] = __builtin_amdgcn_alignbit(use[mi].u[1], use[mi].u[0], shA);
      cv.u[1] = __builtin_amdgcn_alignbit(use[mi].u[2], use[mi].u[1], shA);
      cv.u[2] = __builtin_amdgcn_alignbit(use[mi].u[3], use[mi].u[2], shA);
      cv.u[3] = __builtin_amdgcn_alignbit(use[mi].u[4], use[mi].u[3], shA);
      afrag[mi] = cv.v;
    }

    // B-frags: 5x ds_read_b128
    const int x0    = xc * 32;
    const int slotB = (y + PADV - l15) & 15;
    bf16x8 bfrag[5];
#pragma unroll
    for (int ni = 0; ni < 5; ++ni) {
      const int to = wn * 5 + ni;
      bfrag[ni] = *(const bf16x8*)(ldsB + (to * 16 + slotB) * BSTRIDE + x0 + quad * 8);
    }

#pragma unroll
    for (int mi = 0; mi < 5; ++mi)
#pragma unroll
      for (int ni = 0; ni < 5; ++ni)
        acc[mi][ni] = __builtin_amdgcn_mfma_f32_16x16x32_bf16(
            afrag[mi], bfrag[ni], acc[mi][ni], 0, 0, 0);

    // one barrier per y, at end of its last xc (none after the final y)
    if (xc == 6 && t < 48) __syncthreads();
  };

  for (int ph = 0; ph < 25; ++ph) {
    const int t0 = 2 * ph;
    step(t0, bufA, bufB);
    if (t0 + 1 < 49) step(t0 + 1, bufB, bufA);
  }

  // C/D layout: col = lane&15, row = quad*4 + reg.
  float* outp = partials + (size_t)bid * NCELL;
#pragma unroll
  for (int mi = 0; mi < 5; ++mi)
#pragma unroll
    for (int ni = 0; ni < 5; ++ni) {
      const int mrow = (wm * 5 + mi) * 16 + quad * 4;
      const int ncol = (wn * 5 + ni) * 16 + l15;
#pragma unroll
      for (int r = 0; r < 4; ++r)
        outp[(size_t)(mrow + r) * MD + ncol] = acc[mi][ni][r];
    }
}

// --------------- reduce: 512 partials -> C (fp64) + per-block min + zero out
__global__ __launch_bounds__(256)
void reduce_all(const float* __restrict__ partials, float* __restrict__ Cout,
                float* __restrict__ mins, float* __restrict__ dout) {
  const int c = blockIdx.x * 256 + threadIdx.x;   // 100 blocks x 256 = 25600
  if (c == 0) dout[0] = 0.f;
  double s0 = 0.0, s1 = 0.0, s2 = 0.0, s3 = 0.0;
  const float* base = partials + c;
  for (int p = 0; p < NBLK; p += 4) {
    s0 += (double)base[(size_t)(p + 0) * NCELL];
    s1 += (double)base[(size_t)(p + 1) * NCELL];
    s2 += (double)base[(size_t)(p + 2) * NCELL];
    s3 += (double)base[(size_t)(p + 3) * NCELL];
  }
  const float sf = (float)((s0 + s1) + (s2 + s3));
  Cout[c] = sf;
  const int m  = c / MD;
  const int nn = c - m * MD;
  const bool valid = ((m & 15) < TS) && ((nn & 15) < TS);
  __shared__ float red[256];
  red[threadIdx.x] = valid ? sf : 3.4e38f;
  __syncthreads();
  for (int st = 128; st > 0; st >>= 1) {
    if (threadIdx.x < st)
      red[threadIdx.x] = fminf(red[threadIdx.x], red[threadIdx.x + st]);
    __syncthreads();
  }
  if (threadIdx.x == 0) mins[blockIdx.x] = red[0];
}

// ------------------- loss: per-shift fp64, inline global min over 100 blocks
__global__ __launch_bounds__(128)
void loss_kernel(const float* __restrict__ Cmat, const float* __restrict__ mins,
                 float* __restrict__ dout) {
  const int s   = blockIdx.x;
  const int dy  = s / TS;
  const int dx  = s - dy * TS;
  const int tid = threadIdx.x;
  __shared__ float fm[128];
  __shared__ double q[100];
  __shared__ double sym[100];
  __shared__ double pi[10], pj[10];
  __shared__ double red[128];

  fm[tid] = (tid < 100) ? mins[tid] : 3.4e38f;
  __syncthreads();
  for (int st = 64; st > 0; st >>= 1) {
    if (tid < st) fm[tid] = fminf(fm[tid], fm[tid + st]);
    __syncthreads();
  }
  const double minv = (double)fm[0];
  __syncthreads();

  if (tid < 100) {
    const int n = tid / 10, o = tid - (tid / 10) * 10;
    const double v = (double)Cmat[(size_t)(n * 16 + dx) * MD + (o * 16 + dy)];
    q[tid] = v - minv + LEPS;
  }
  __syncthreads();
  red[tid] = (tid < 100) ? q[tid] : 0.0;
  __syncthreads();
  for (int st = 64; st > 0; st >>= 1) {
    if (tid < st) red[tid] += red[tid + st];
    __syncthreads();
  }
  const double Z = red[0];
  __syncthreads();
  if (tid < 100) {
    const int n = tid / 10, o = tid - (tid / 10) * 10;
    sym[tid] = (q[n * 10 + o] + q[o * 10 + n]) * 0.5 / Z;
  }
  __syncthreads();
  if (tid < 10) {
    double a = 0.0, bsum = 0.0;
    for (int n2 = 0; n2 < 10; ++n2) {
      a    += sym[n2 * 10 + tid];
      bsum += sym[tid * 10 + n2];
    }
    pi[tid] = a;
    pj[tid] = bsum;
  }
  __syncthreads();
  double term = 0.0;
  if (tid < 100) {
    const int n = tid / 10, o = tid - (tid / 10) * 10;
    const double sp = sym[tid];
    term = -sp * (log(sp + LEPS) - log(pi[o] + LEPS) - log(pj[n] + LEPS));
  }
  red[tid] = term;
  __syncthreads();
  for (int st = 64; st > 0; st >>= 1) {
    if (tid < st) red[tid] += red[tid + st];
    __syncthreads();
  }
  if (tid == 0) atomicAdd(dout, (float)(red[0] / (double)(TS * TS)));
}

extern "C" void kernel_launch(void* const* d_in, const int* in_sizes, int n_in,
                              void* d_out, int out_size, void* d_ws, size_t ws_size,
                              hipStream_t stream) {
  const float* xo = (const float*)d_in[0];
  const float* xt = (const float*)d_in[1];
  float* ws       = (float*)d_ws;

  float* partials = ws;                                  // 512*25600 f32 = 52.4 MB
  float* Cmat     = partials + (size_t)NBLK * NCELL;     // 25600
  float* mins     = Cmat + NCELL;                        // 100 (pad 128)
  unsigned short* bpad = (unsigned short*)(mins + 128);  // 160*240*232 bf16 = 17.8 MB
  uint32_t* apad  = (uint32_t*)(bpad + (size_t)160 * BPH * BSTRIDE);  // 17.2 MB
  float* out      = (float*)d_out;

  hipLaunchKernelGGL(prep,       dim3(BPREP_BLOCKS + APREP_BLOCKS), dim3(256), 0, stream,
                     xo, xt, bpad, apad);
  hipLaunchKernelGGL(corr_gemm,  dim3(NBLK), dim3(256), 0, stream, apad, bpad, partials);
  hipLaunchKernelGGL(reduce_all, dim3(100),  dim3(256), 0, stream, partials, Cmat, mins, out);
  hipLaunchKernelGGL(loss_kernel,dim3(225),  dim3(128), 0, stream, Cmat, mins, out);
}

// Round 5
// 166.388 us; speedup vs baseline: 1.0766x; 1.0766x over previous
//
#include <hip/hip_runtime.h>
#include <stdint.h>
#include <math.h>

// ---------------------------------------------------------------------------
// IID segmentation loss on MI355X.  Round 5.
//
// C[(n,dx)][(o,dy)] = sum_{b,y,x} xo[b,n,y,x+dx-7] * xt[b,o,y+7-dy,x]
// R4 findings: K1 stalls on cold-HBM A prefetch (distance-1 too short at
// 8 waves/CU); total time scales with ws size (harness re-poisons d_ws).
// R5: 256 blocks x 512 threads, TY=14, K-SPLIT over xc parity between wave
// groups kw=0 (xc 0,2,4,6) and kw=1 (xc 1,3,5  + B-DMA duty).  Per-wave step
// is ~2x longer -> distance-1 A prefetch covers the ~900cyc HBM miss.
// K-halves merged via 2-round LDS exchange (reuses ldsB) -> partials 256
// slots (ws 88->62 MB, WRITE halves).  Tail: reduce_all 400 blocks.
// ---------------------------------------------------------------------------

#define PADV 7
#define TS 15
#define KCLS 10
#define HH 224
#define WW 224
#define MD 160
#define NCELL (MD*MD)
#define NBLK 256           // split-K partial count (one per block)
#define TY 14              // y rows per K1 block (16 strips * 14 = 224)
#define BSTRIDE 232
#define BPH 240
#define ADW 120            // apad dwords per (cls,y) row (240 bf16 elems)
#define LEPS 1e-16

typedef __attribute__((ext_vector_type(4))) float f32x4;
typedef __attribute__((ext_vector_type(8))) short bf16x8;

__device__ __forceinline__ unsigned short f2bf(float f) {
  union { float f; uint32_t u; } v; v.f = f;
  return (unsigned short)((v.u + 0x7FFFu + ((v.u >> 16) & 1u)) >> 16);
}

__device__ __forceinline__ void glds16(const unsigned short* g, unsigned short* l) {
  __builtin_amdgcn_global_load_lds(
      (const __attribute__((address_space(1))) unsigned int*)g,
      (__attribute__((address_space(3))) unsigned int*)l, 16, 0, 0);
}

struct U5 { uint32_t u[5]; };

__device__ __forceinline__ void ldA5(const uint32_t* p, U5& d) {
  uint4 t;
  __builtin_memcpy(&t, p, 16);
  d.u[0] = t.x; d.u[1] = t.y; d.u[2] = t.z; d.u[3] = t.w;
  d.u[4] = p[4];
}

// ---------------------------------------------------- prep: apad + bpad
#define BPREP_BLOCKS 4350   // 160*240*29 threads
#define APREP_BLOCKS 4200   // 160*224*30 threads
__global__ __launch_bounds__(256)
void prep(const float* __restrict__ xo, const float* __restrict__ xt,
          unsigned short* __restrict__ bp, uint32_t* __restrict__ ap) {
  if (blockIdx.x < BPREP_BLOCKS) {
    const int idx   = blockIdx.x * 256 + threadIdx.x;
    const int rowid = idx / 29;
    const int chunk = idx - rowid * 29;
    const int x0    = chunk * 8;
    const int yy    = rowid % BPH;
    const int cls   = rowid / BPH;
    const int row   = yy - PADV;
    union { unsigned short h[8]; uint4 v; } out;
    if (row >= 0 && row < HH && x0 < WW) {
      const float* src = xt + ((size_t)cls * HH + row) * WW + x0;
#pragma unroll
      for (int j = 0; j < 8; ++j) out.h[j] = f2bf(src[j]);
    } else {
      out.v = make_uint4(0u, 0u, 0u, 0u);
    }
    *(uint4*)(bp + (size_t)rowid * BSTRIDE + x0) = out.v;
  } else {
    const int idx   = (blockIdx.x - BPREP_BLOCKS) * 256 + threadIdx.x;
    const int rowid = idx / 30;               // cls*224 + y
    const int wg    = idx - rowid * 30;
    const float* src = xo + (size_t)rowid * WW;
    float e[8];
#pragma unroll
    for (int j = 0; j < 8; ++j) {
      const int x = 8 * wg + j - PADV;
      e[j] = (x >= 0 && x < WW) ? src[x] : 0.f;
    }
    union { uint32_t u[4]; uint4 v; } o;
#pragma unroll
    for (int k = 0; k < 4; ++k)
      o.u[k] = (uint32_t)f2bf(e[2 * k]) | ((uint32_t)f2bf(e[2 * k + 1]) << 16);
    *(uint4*)(ap + (size_t)rowid * ADW + 4 * wg) = o.v;
  }
}

// ---------------------------------------------------------------- K1: GEMM
__global__ __launch_bounds__(512, 1)
void corr_gemm(const uint32_t* __restrict__ apad,
               const unsigned short* __restrict__ bpad,
               float* __restrict__ partials) {
  __shared__ __align__(16) unsigned short ldsB[KCLS * 16 * BSTRIDE];  // 74240 B

  const int tid  = threadIdx.x;
  const int bid  = blockIdx.x;
  const int b    = bid >> 4;               // 16 batches
  const int y0   = (bid & 15) * TY;        // 16 strips of 14 rows

  const int lane = tid & 63;
  const int wv   = tid >> 6;               // 0..7
  const int wm   = wv & 1;
  const int wn   = (wv >> 1) & 1;
  const int kw   = wv >> 2;                // K-split group (xc parity)
  const int quad = lane >> 4;
  const int l15  = lane & 15;

  const int shA    = (l15 & 1) << 4;
  const int laneWd = quad * 4 + (l15 >> 1);

  f32x4 acc[5][5];
#pragma unroll
  for (int i = 0; i < 5; ++i)
#pragma unroll
    for (int j = 0; j < 5; ++j) acc[i][j] = (f32x4){0.f, 0.f, 0.f, 0.f};

  const unsigned short* Bb = bpad + (size_t)b * KCLS * BPH * BSTRIDE;
  const uint32_t* Abase = apad + ((size_t)(b * KCLS + wm * 5) * HH) * ADW;

  // prologue: async DMA B rows y0-7..y0+7 (150 class-rows, all 8 waves)
  for (int pr = wv; pr < 15 * KCLS; pr += 8) {
    const int r15  = pr / KCLS;
    const int o    = pr - r15 * KCLS;
    const int yy   = y0 + r15;
    const int slot = (y0 - PADV + r15) & 15;
    if (lane < 29)
      glds16(Bb + ((size_t)o * BPH + yy) * BSTRIDE + lane * 8,
             ldsB + (o * 16 + slot) * BSTRIDE);
  }

  U5 bufA[5], bufB[5];
  // prologue A prefetch: first step (y0, xc=kw)
#pragma unroll
  for (int mi = 0; mi < 5; ++mi)
    ldA5(Abase + ((size_t)mi * HH + y0) * ADW + kw * 16 + laneWd, bufA[mi]);

  __syncthreads();  // drains prologue DMA

  auto stepf = [&](int y, int xc, U5 (&use)[5], U5 (&pre)[5],
                   int pny, int pnxc, bool dopre) {
    if (dopre) {
#pragma unroll
      for (int mi = 0; mi < 5; ++mi)
        ldA5(Abase + ((size_t)mi * HH + pny) * ADW + pnxc * 16 + laneWd, pre[mi]);
    }
    bf16x8 afrag[5];
#pragma unroll
    for (int mi = 0; mi < 5; ++mi) {
      union { uint32_t u[4]; bf16x8 v; } cv;
      cv.u[0] = __builtin_amdgcn_alignbit(use[mi].u[1], use[mi].u[0], shA);
      cv.u[1] = __builtin_amdgcn_alignbit(use[mi].u[2], use[mi].u[1], shA);
      cv.u[2] = __builtin_amdgcn_alignbit(use[mi].u[3], use[mi].u[2], shA);
      cv.u[3] = __builtin_amdgcn_alignbit(use[mi].u[4], use[mi].u[3], shA);
      afrag[mi] = cv.v;
    }
    const int x0    = xc * 32;
    const int slotB = (y + PADV - l15) & 15;
    bf16x8 bfrag[5];
#pragma unroll
    for (int ni = 0; ni < 5; ++ni) {
      const int to = wn * 5 + ni;
      bfrag[ni] = *(const bf16x8*)(ldsB + (to * 16 + slotB) * BSTRIDE + x0 + quad * 8);
    }
#pragma unroll
    for (int mi = 0; mi < 5; ++mi)
#pragma unroll
      for (int ni = 0; ni < 5; ++ni)
        acc[mi][ni] = __builtin_amdgcn_mfma_f32_16x16x32_bf16(
            afrag[mi], bfrag[ni], acc[mi][ni], 0, 0, 0);
  };

  auto dmaB = [&](int y) {  // called by kw=1 waves only
    const int yy   = y + 15;          // row y+8 -> yy = row+7
    const int slot = (y + 8) & 15;
    for (int ro = wv - 4; ro < KCLS; ro += 4)
      if (lane < 29)
        glds16(Bb + ((size_t)ro * BPH + yy) * BSTRIDE + lane * 8,
               ldsB + (ro * 16 + slot) * BSTRIDE);
  };

  if (kw == 0) {
    // xc 0,2,4,6 per y: 4 steps -> buffer parity restored each y
#pragma unroll 1
    for (int iy = 0; iy < TY; ++iy) {
      const int y = y0 + iy;
      const bool lastY = (iy == TY - 1);
      stepf(y, 0, bufA, bufB, y, 2, true);
      stepf(y, 2, bufB, bufA, y, 4, true);
      stepf(y, 4, bufA, bufB, y, 6, true);
      stepf(y, 6, bufB, bufA, y + 1, 0, !lastY);
      if (!lastY) __syncthreads();
    }
  } else {
    // xc 1,3,5 per y (3 steps) + B-DMA duty; unroll y-pairs for parity
#pragma unroll 1
    for (int iy2 = 0; iy2 < TY; iy2 += 2) {
      {
        const int y = y0 + iy2;
        dmaB(y);
        stepf(y, 1, bufA, bufB, y, 3, true);
        stepf(y, 3, bufB, bufA, y, 5, true);
        stepf(y, 5, bufA, bufB, y + 1, 1, true);
        __syncthreads();
      }
      {
        const int iy = iy2 + 1;
        const int y  = y0 + iy;
        const bool lastY = (iy == TY - 1);
        if (!lastY) dmaB(y);
        stepf(y, 1, bufB, bufA, y, 3, true);
        stepf(y, 3, bufA, bufB, y, 5, true);
        stepf(y, 5, bufB, bufA, y + 1, 1, !lastY);
        if (!lastY) __syncthreads();
      }
    }
  }

  // ---- epilogue: merge K-halves via LDS (2 rounds), kw0 stores ----
  __syncthreads();
  float* ex = (float*)ldsB;
  const int w1 = wm * 2 + wn;
  float* outp = partials + (size_t)bid * NCELL;
#pragma unroll
  for (int rd = 0; rd < 2; ++rd) {
    const int mib = (rd == 0) ? 0 : 3;
    const int nmi = (rd == 0) ? 3 : 2;
    if (kw == 1) {
#pragma unroll
      for (int dmi = 0; dmi < 3; ++dmi) {
        if (dmi >= nmi) break;
#pragma unroll
        for (int ni = 0; ni < 5; ++ni)
          *(f32x4*)(ex + (((w1 * 3 + dmi) * 5 + ni) << 8) + lane * 4) =
              acc[mib + dmi][ni];
      }
    }
    __syncthreads();
    if (kw == 0) {
#pragma unroll
      for (int dmi = 0; dmi < 3; ++dmi) {
        if (dmi >= nmi) break;
        const int mi = mib + dmi;
#pragma unroll
        for (int ni = 0; ni < 5; ++ni) {
          const f32x4 other = *(const f32x4*)(ex + (((w1 * 3 + dmi) * 5 + ni) << 8) + lane * 4);
          const int mrow = (wm * 5 + mi) * 16 + quad * 4;
          const int ncol = (wn * 5 + ni) * 16 + l15;
#pragma unroll
          for (int r = 0; r < 4; ++r)
            outp[(size_t)(mrow + r) * MD + ncol] = acc[mi][ni][r] + other[r];
        }
      }
    }
    __syncthreads();
  }
}

// ------- reduce: 256 partials -> C (fp64) + per-block min + zero d_out
__global__ __launch_bounds__(256)
void reduce_all(const float* __restrict__ partials, float* __restrict__ Cout,
                float* __restrict__ mins, float* __restrict__ dout) {
  const int blk = blockIdx.x;             // 400 blocks x 64 cells
  const int t   = threadIdx.x;
  const int c   = blk * 64 + (t & 63);
  const int ps  = t >> 6;                 // 4-way split over partials
  if (blk == 0 && t == 0) dout[0] = 0.f;
  double s0 = 0.0, s1 = 0.0;
  const float* base = partials + c;
  for (int p = ps * 64; p < ps * 64 + 64; p += 2) {
    s0 += (double)base[(size_t)p * NCELL];
    s1 += (double)base[(size_t)(p + 1) * NCELL];
  }
  __shared__ double red[256];
  red[t] = s0 + s1;
  __syncthreads();
  if (t < 64) {
    const double tot = red[t] + red[t + 64] + red[t + 128] + red[t + 192];
    const float sf = (float)tot;
    Cout[c] = sf;
    const int m  = c / MD;
    const int nn = c - m * MD;
    const bool valid = ((m & 15) < TS) && ((nn & 15) < TS);
    float v = valid ? sf : 3.4e38f;
#pragma unroll
    for (int off = 32; off > 0; off >>= 1)
      v = fminf(v, __shfl_down(v, off));
    if (t == 0) mins[blk] = v;
  }
}

// ------------------- loss: per-shift fp64, inline global min (400 mins)
__global__ __launch_bounds__(128)
void loss_kernel(const float* __restrict__ Cmat, const float* __restrict__ mins,
                 float* __restrict__ dout) {
  const int s   = blockIdx.x;
  const int dy  = s / TS;
  const int dx  = s - dy * TS;
  const int tid = threadIdx.x;
  __shared__ float fm[128];
  __shared__ double q[100];
  __shared__ double sym[100];
  __shared__ double pi[10], pj[10];
  __shared__ double red[128];

  float v = 3.4e38f;
  for (int i = tid; i < 400; i += 128) v = fminf(v, mins[i]);
  fm[tid] = v;
  __syncthreads();
  for (int st = 64; st > 0; st >>= 1) {
    if (tid < st) fm[tid] = fminf(fm[tid], fm[tid + st]);
    __syncthreads();
  }
  const double minv = (double)fm[0];
  __syncthreads();

  if (tid < 100) {
    const int n = tid / 10, o = tid - (tid / 10) * 10;
    const double vv = (double)Cmat[(size_t)(n * 16 + dx) * MD + (o * 16 + dy)];
    q[tid] = vv - minv + LEPS;
  }
  __syncthreads();
  red[tid] = (tid < 100) ? q[tid] : 0.0;
  __syncthreads();
  for (int st = 64; st > 0; st >>= 1) {
    if (tid < st) red[tid] += red[tid + st];
    __syncthreads();
  }
  const double Z = red[0];
  __syncthreads();
  if (tid < 100) {
    const int n = tid / 10, o = tid - (tid / 10) * 10;
    sym[tid] = (q[n * 10 + o] + q[o * 10 + n]) * 0.5 / Z;
  }
  __syncthreads();
  if (tid < 10) {
    double a = 0.0, bsum = 0.0;
    for (int n2 = 0; n2 < 10; ++n2) {
      a    += sym[n2 * 10 + tid];
      bsum += sym[tid * 10 + n2];
    }
    pi[tid] = a;
    pj[tid] = bsum;
  }
  __syncthreads();
  double term = 0.0;
  if (tid < 100) {
    const int n = tid / 10, o = tid - (tid / 10) * 10;
    const double sp = sym[tid];
    term = -sp * (log(sp + LEPS) - log(pi[o] + LEPS) - log(pj[n] + LEPS));
  }
  red[tid] = term;
  __syncthreads();
  for (int st = 64; st > 0; st >>= 1) {
    if (tid < st) red[tid] += red[tid + st];
    __syncthreads();
  }
  if (tid == 0) atomicAdd(dout, (float)(red[0] / (double)(TS * TS)));
}

extern "C" void kernel_launch(void* const* d_in, const int* in_sizes, int n_in,
                              void* d_out, int out_size, void* d_ws, size_t ws_size,
                              hipStream_t stream) {
  const float* xo = (const float*)d_in[0];
  const float* xt = (const float*)d_in[1];
  float* ws       = (float*)d_ws;

  float* partials = ws;                                  // 256*25600 f32 = 26.2 MB
  float* Cmat     = partials + (size_t)NBLK * NCELL;     // 25600
  float* mins     = Cmat + NCELL;                        // 400 (pad 512)
  unsigned short* bpad = (unsigned short*)(mins + 512);  // 17.8 MB
  uint32_t* apad  = (uint32_t*)(bpad + (size_t)160 * BPH * BSTRIDE);  // 17.2 MB
  float* out      = (float*)d_out;

  hipLaunchKernelGGL(prep,       dim3(BPREP_BLOCKS + APREP_BLOCKS), dim3(256), 0, stream,
                     xo, xt, bpad, apad);
  hipLaunchKernelGGL(corr_gemm,  dim3(256), dim3(512), 0, stream, apad, bpad, partials);
  hipLaunchKernelGGL(reduce_all, dim3(400), dim3(256), 0, stream, partials, Cmat, mins, out);
  hipLaunchKernelGGL(loss_kernel,dim3(225), dim3(128), 0, stream, Cmat, mins, out);
}